// Round 5
// baseline (6438.719 us; speedup 1.0000x reference)
//
#include <hip/hip_runtime.h>
#include <hip/hip_fp16.h>

typedef _Float16 f16;
typedef _Float16 f16x8 __attribute__((ext_vector_type(8)));
typedef float f32x16 __attribute__((ext_vector_type(16)));

#define T_N 512
#define DSTEPS 48
#define TOTSTEPS 560
#define NWG 64

// ---- ws layout (bytes) ----
#define OFF_WHHE 0ull
#define SZ_WHH   (4096ull*1024*2)          // 8 MB
#define OFF_WHHD (OFF_WHHE + SZ_WHH)
#define OFF_WIHE (OFF_WHHD + SZ_WHH)
#define SZ_WIH   (4096ull*64*2)            // 512 KB
#define OFF_WIHD (OFF_WIHE + SZ_WIH)
#define OFF_WFC  (OFF_WIHD + SZ_WIH)
#define SZ_WFC   (64ull*1024*2)            // 128 KB
#define OFF_XP   (OFF_WFC + SZ_WFC)
#define SZ_XP    (512ull*4096*2)           // 4 MB
#define OFF_Y0   (OFF_XP + SZ_XP)
#define SZ_Y0    (4096ull*2)
#define OFF_BE   (OFF_Y0 + SZ_Y0)
#define OFF_BD   (OFF_BE + 4096ull*4)
#define OFF_FLG  (OFF_BD + 4096ull*4)
#define SZ_FLG   (561ull*256*4)            // per-step, per-(WG,wave) flags
#define OFF_H    ((OFF_FLG + SZ_FLG + 255ull) & ~255ull)
// h of step t: 65536 f16 at OFF_H + t*131072, layout [w_src(64)][b(64)][u(16)]

// dynamic LDS: gates [2 parity][4 K-quarter][64 n][66 m] + bias [2][64]
#define LDS_BYTES ((2*4*64*66 + 2*64) * 4)   // 135,680 B

// ============================ prologue: pack to fp16 fragment-linear ============================
__global__ void prologue(const float* __restrict__ x, const float* __restrict__ y0,
    const float* __restrict__ wihE, const float* __restrict__ whhE,
    const float* __restrict__ bihE, const float* __restrict__ bhhE,
    const float* __restrict__ wihD, const float* __restrict__ whhD,
    const float* __restrict__ bihD, const float* __restrict__ bhhD,
    const float* __restrict__ wfc, char* __restrict__ ws)
{
  const long long gid = (long long)blockIdx.x * 256 + threadIdx.x;
  const long long gsz = (long long)gridDim.x * 256;
  f16* whhEp = (f16*)(ws + OFF_WHHE);
  f16* whhDp = (f16*)(ws + OFF_WHHD);
  f16* wihEp = (f16*)(ws + OFF_WIHE);
  f16* wihDp = (f16*)(ws + OFF_WIHD);
  f16* wfcp  = (f16*)(ws + OFF_WFC);
  f16* xp    = (f16*)(ws + OFF_XP);
  f16* y0p   = (f16*)(ws + OFF_Y0);
  float* be  = (float*)(ws + OFF_BE);
  float* bd  = (float*)(ws + OFF_BD);

  // Whh packs: idx = w*65536 + ks*32768 + i*16384 + kk*512 + lane*8 + j
  for (long long idx = gid; idx < 4194304ll; idx += gsz) {
    int j = (int)idx & 7, l = (int)(idx >> 3) & 63, kk = (int)(idx >> 9) & 31;
    int i = (int)(idx >> 14) & 1, ks = (int)(idx >> 15) & 1, w = (int)(idx >> 16);
    int nl = i * 32 + (l & 31);
    int grow = (nl >> 4) * 1024 + w * 16 + (nl & 15);
    int k = ks * 512 + kk * 16 + ((l >> 5) << 3) + j;
    whhEp[idx] = (f16)whhE[(long long)grow * 1024 + k];
    whhDp[idx] = (f16)whhD[(long long)grow * 1024 + k];
  }
  // Wih packs: idx = w*4096 + ks*2048 + i*1024 + kx*512 + lane*8 + j
  for (long long idx = gid; idx < 262144ll; idx += gsz) {
    int j = (int)idx & 7, l = (int)(idx >> 3) & 63, kx = (int)(idx >> 9) & 1;
    int i = (int)(idx >> 10) & 1, ks = (int)(idx >> 11) & 1, w = (int)(idx >> 12);
    int nl = i * 32 + (l & 31);
    int grow = (nl >> 4) * 1024 + w * 16 + (nl & 15);
    int k = (ks * 2 + kx) * 16 + ((l >> 5) << 3) + j;
    wihEp[idx] = (f16)wihE[grow * 64 + k];
    wihDp[idx] = (f16)wihD[grow * 64 + k];
  }
  // Wfc pack: idx = ks*32768 + i*16384 + kk*512 + lane*8 + j
  for (long long idx = gid; idx < 65536ll; idx += gsz) {
    int j = (int)idx & 7, l = (int)(idx >> 3) & 63, kk = (int)(idx >> 9) & 31;
    int i = (int)(idx >> 14) & 1, ks = (int)(idx >> 15) & 1;
    int o = i * 32 + (l & 31);
    int k = ks * 512 + kk * 16 + ((l >> 5) << 3) + j;
    wfcp[idx] = (f16)wfc[o * 1024 + k];
  }
  // x pack: [t][kkx(4)][b(64)][16]
  for (long long idx = gid; idx < 2097152ll; idx += gsz) {
    int kw = (int)idx & 15, b = (int)(idx >> 4) & 63, kkx = (int)(idx >> 10) & 3, t = (int)(idx >> 12);
    xp[idx] = (f16)x[(long long)b * 32768 + t * 64 + kkx * 16 + kw];
  }
  // y0 pack: [kkx][b][16]
  for (long long idx = gid; idx < 4096ll; idx += gsz) {
    int kw = (int)idx & 15, b = (int)(idx >> 4) & 63, kkx = (int)(idx >> 10) & 3;
    y0p[idx] = (f16)y0[b * 64 + kkx * 16 + kw];
  }
  // combined biases
  for (long long idx = gid; idx < 4096ll; idx += gsz) {
    be[idx] = bihE[idx] + bhhE[idx];
    bd[idx] = bihD[idx] + bhhD[idx];
  }
  // flags need no init: poison 0xAAAAAAAA != 1, producers store 1
}

// ============================ persistent LSTM kernel ============================
__device__ __forceinline__ float sigf(float x) { return 1.0f / (1.0f + __expf(-x)); }
__device__ __forceinline__ float tanhfast(float x) {
  x = fminf(fmaxf(x, -15.f), 15.f);
  float e = __expf(2.0f * x);
  return (e - 1.0f) / (e + 1.0f);
}

#define MFMA(a,b,c) __builtin_amdgcn_mfma_f32_32x32x16_f16((a),(b),(c),0,0,0)
#define LGD(par,qq,n,m) lds_g[((((par)*4+(qq))*64+(n))*66)+(m)]

__launch_bounds__(256, 1)
__global__ void lstm_persist(char* __restrict__ ws, float* __restrict__ out,
                             const float* __restrict__ bfc)
{
  const int w    = blockIdx.x;      // owns hidden units [w*16, w*16+16)
  const int tid  = threadIdx.x;
  const int lane = tid & 63;
  const int q    = tid >> 6;        // wave = K-quarter; also batch-quarter in cell phase

  const f16* whhEp = (const f16*)(ws + OFF_WHHE) + (size_t)w * 65536;
  const f16* whhDp = (const f16*)(ws + OFF_WHHD) + (size_t)w * 65536;
  const f16* wihEp = (const f16*)(ws + OFF_WIHE) + (size_t)w * 4096;
  const f16* wihDp = (const f16*)(ws + OFF_WIHD) + (size_t)w * 4096;
  const f16* wfcp  = (const f16*)(ws + OFF_WFC);
  const f16* xp    = (const f16*)(ws + OFF_XP);
  const f16* y0p   = (const f16*)(ws + OFF_Y0);
  const float* be  = (const float*)(ws + OFF_BE);
  const float* bd  = (const float*)(ws + OFF_BD);
  unsigned* flags  = (unsigned*)(ws + OFF_FLG);
  f16* hb          = (f16*)(ws + OFF_H);

  extern __shared__ char smem[];
  float* lds_g  = (float*)smem;                          // [2][4][64][66]
  float* bias_s = (float*)(smem + (size_t)2*4*64*66*4);  // [2][64]

  if (tid < 64) {
    int g4 = tid >> 4, u = tid & 15;
    bias_s[tid]      = be[g4 * 1024 + w * 16 + u];
    bias_s[64 + tid] = bd[g4 * 1024 + w * 16 + u];
  }

  // A-frag offsets for the two M(batch)-tiles
  const int aoff0 = (lane & 31) * 16 + (lane >> 5) * 8;
  const int aoff1 = (32 + (lane & 31)) * 16 + (lane >> 5) * 8;
  const int boff  = lane * 8;
  const int bq    = (q >> 1) * 32768 + (q & 1) * 8192;   // K-quarter base in Whh/Wfc pack
  const int wq    = (q >> 1) * 2048 + (q & 1) * 512;     // K-quarter base in Wih pack
  // cell phase: wave q owns batches [16q,16q+16)
  const int bsel  = tid >> 2;
  const int u0    = (tid & 3) * 4;

  // Whh B-fragments resident in registers: [n-tile][kk]
  f16x8 bf0[16], bf1[16];
#pragma unroll
  for (int kk = 0; kk < 16; ++kk) {
    bf0[kk] = *(const f16x8*)(whhEp + bq + kk * 512 + boff);
    bf1[kk] = *(const f16x8*)(whhEp + bq + 16384 + kk * 512 + boff);
  }

  float c0 = 0.f, c1 = 0.f, c2 = 0.f, c3 = 0.f;
  __syncthreads();   // bias_s ready

#pragma unroll 1
  for (int t = 0; t < TOTSTEPS; ++t) {
    const bool enc = (t < T_N);
    if (t == T_N) {   // register-only decoder weight swap
#pragma unroll
      for (int kk = 0; kk < 16; ++kk) {
        bf0[kk] = *(const f16x8*)(whhDp + bq + kk * 512 + boff);
        bf1[kk] = *(const f16x8*)(whhDp + bq + 16384 + kk * 512 + boff);
      }
    }

    // x-projection (independent of h)
    const f16* xblk = enc ? (xp + (size_t)t * 4096) : y0p;
    const f16* wihp = enc ? wihEp : wihDp;
    f16x8 xa0 = *(const f16x8*)(xblk + q * 1024 + aoff0);
    f16x8 xa1 = *(const f16x8*)(xblk + q * 1024 + aoff1);
    f16x8 wf0 = *(const f16x8*)(wihp + wq + boff);
    f16x8 wf1 = *(const f16x8*)(wihp + wq + 1024 + boff);

    f32x16 a00, a01, a10, a11;
#pragma unroll
    for (int i = 0; i < 16; ++i) { a00[i] = 0.f; a01[i] = 0.f; a10[i] = 0.f; a11[i] = 0.f; }
    a00 = MFMA(xa0, wf0, a00); a01 = MFMA(xa0, wf1, a01);
    a10 = MFMA(xa1, wf0, a10); a11 = MFMA(xa1, wf1, a11);

    if (t > 0) {
      // wave-local ballot poll: 64 flags = producers (w_src in [16q,+16)) x (p in 0..3)
      const unsigned* fl = flags + (size_t)t * 256 + q * 64 + lane;
      unsigned v;
      do {
        v = __hip_atomic_load(fl, __ATOMIC_RELAXED, __HIP_MEMORY_SCOPE_AGENT);
      } while (!__all(v == 1u));

      // burst-load this wave's K-quarter of h(t-1), both M-tiles: 32 loads in flight
      const f16* hblk = hb + (size_t)(t - 1) * 65536;
      f16x8 af0[16], af1[16];
#pragma unroll
      for (int kk = 0; kk < 16; ++kk) {
        af0[kk] = *(const f16x8*)(hblk + (size_t)(q * 16 + kk) * 1024 + aoff0);
        af1[kk] = *(const f16x8*)(hblk + (size_t)(q * 16 + kk) * 1024 + aoff1);
      }
#pragma unroll
      for (int kk = 0; kk < 16; ++kk) {
        a00 = MFMA(af0[kk], bf0[kk], a00);
        a01 = MFMA(af0[kk], bf1[kk], a01);
        a10 = MFMA(af1[kk], bf0[kk], a10);
        a11 = MFMA(af1[kk], bf1[kk], a11);
      }
    }

    // K-quarter partials -> parity LDS buffer
    const int par = t & 1;
    {
      const int n0 = lane & 31;
      const int mb = (lane >> 5) << 2;
#pragma unroll
      for (int r = 0; r < 16; ++r) {
        const int m0 = mb + (r & 3) + ((r >> 2) << 3);
        LGD(par, q, n0,      m0)      = a00[r];
        LGD(par, q, 32 + n0, m0)      = a01[r];
        LGD(par, q, n0,      32 + m0) = a10[r];
        LGD(par, q, 32 + n0, 32 + m0) = a11[r];
      }
    }
    __syncthreads();   // the only barrier in the step

    // cell update: thread -> (batch bsel, unit-locals u0..u0+3)
    const float* bs = enc ? bias_s : (bias_s + 64);
    union { unsigned long long u64; f16 h4[4]; } hu;
    float cc[4] = {c0, c1, c2, c3};
#pragma unroll
    for (int j = 0; j < 4; ++j) {
      const int u = u0 + j;
      float ig = LGD(par,0,u,bsel)      + LGD(par,1,u,bsel)      + LGD(par,2,u,bsel)      + LGD(par,3,u,bsel)      + bs[u];
      float fg = LGD(par,0,16+u,bsel)   + LGD(par,1,16+u,bsel)   + LGD(par,2,16+u,bsel)   + LGD(par,3,16+u,bsel)   + bs[16+u];
      float gg = LGD(par,0,32+u,bsel)   + LGD(par,1,32+u,bsel)   + LGD(par,2,32+u,bsel)   + LGD(par,3,32+u,bsel)   + bs[32+u];
      float og = LGD(par,0,48+u,bsel)   + LGD(par,1,48+u,bsel)   + LGD(par,2,48+u,bsel)   + LGD(par,3,48+u,bsel)   + bs[48+u];
      float cn = sigf(fg) * cc[j] + sigf(ig) * tanhfast(gg);
      cc[j] = cn;
      hu.h4[j] = (f16)(sigf(og) * tanhfast(cn));
    }
    c0 = cc[0]; c1 = cc[1]; c2 = cc[2]; c3 = cc[3];

    // write-through h slice (wave q covers a contiguous 512 B), then per-wave flag
    {
      f16* dst = hb + (size_t)t * 65536 + (size_t)w * 1024 + bsel * 16 + u0;
      unsigned long long addr = (unsigned long long)(size_t)dst;
      asm volatile("global_store_dwordx2 %0, %1, off sc0 sc1" : : "v"(addr), "v"(hu.u64) : "memory");
    }
    asm volatile("s_waitcnt vmcnt(0)" ::: "memory");   // wave-level drain of this wave's stores
    if (lane == 0) {
      __hip_atomic_store(flags + (size_t)(t + 1) * 256 + w * 4 + q, 1u,
                         __ATOMIC_RELEASE, __HIP_MEMORY_SCOPE_AGENT);
    }
  }

  // ---- FC epilogue: WG w<48 computes out[:, w*64..+64) from h of step 512+w ----
  if (w < DSTEPS) {
    const int s = T_N + 1 + w;   // flag index of h produced at step 512+w
#pragma unroll
    for (int kk = 0; kk < 16; ++kk) {
      bf0[kk] = *(const f16x8*)(wfcp + bq + kk * 512 + boff);
      bf1[kk] = *(const f16x8*)(wfcp + bq + 16384 + kk * 512 + boff);
    }
    {
      const unsigned* fl = flags + (size_t)s * 256 + q * 64 + lane;
      unsigned v;
      do {
        v = __hip_atomic_load(fl, __ATOMIC_RELAXED, __HIP_MEMORY_SCOPE_AGENT);
      } while (!__all(v == 1u));
    }
    const f16* hblk = hb + (size_t)(s - 1) * 65536;
    f16x8 af0[16], af1[16];
#pragma unroll
    for (int kk = 0; kk < 16; ++kk) {
      af0[kk] = *(const f16x8*)(hblk + (size_t)(q * 16 + kk) * 1024 + aoff0);
      af1[kk] = *(const f16x8*)(hblk + (size_t)(q * 16 + kk) * 1024 + aoff1);
    }
    f32x16 a00, a01, a10, a11;
#pragma unroll
    for (int i = 0; i < 16; ++i) { a00[i] = 0.f; a01[i] = 0.f; a10[i] = 0.f; a11[i] = 0.f; }
#pragma unroll
    for (int kk = 0; kk < 16; ++kk) {
      a00 = MFMA(af0[kk], bf0[kk], a00);
      a01 = MFMA(af0[kk], bf1[kk], a01);
      a10 = MFMA(af1[kk], bf0[kk], a10);
      a11 = MFMA(af1[kk], bf1[kk], a11);
    }
    {
      const int n0 = lane & 31;
      const int mb = (lane >> 5) << 2;
#pragma unroll
      for (int r = 0; r < 16; ++r) {
        const int m0 = mb + (r & 3) + ((r >> 2) << 3);
        LGD(0, q, n0,      m0)      = a00[r];
        LGD(0, q, 32 + n0, m0)      = a01[r];
        LGD(0, q, n0,      32 + m0) = a10[r];
        LGD(0, q, 32 + n0, 32 + m0) = a11[r];
      }
    }
    __syncthreads();
    // thread -> batch bsel, features f0..f0+15 (ALL 64 features covered)
    const int f0 = (tid & 3) * 16;
    float* op = out + (size_t)bsel * 3072 + w * 64 + f0;
#pragma unroll
    for (int c4 = 0; c4 < 4; ++c4) {
      float v4[4];
#pragma unroll
      for (int j = 0; j < 4; ++j) {
        const int f = f0 + c4 * 4 + j;
        v4[j] = LGD(0,0,f,bsel) + LGD(0,1,f,bsel) + LGD(0,2,f,bsel) + LGD(0,3,f,bsel) + bfc[f];
      }
      *(float4*)(op + c4 * 4) = make_float4(v4[0], v4[1], v4[2], v4[3]);
    }
  }
}

// ============================ launch ============================
extern "C" void kernel_launch(void* const* d_in, const int* in_sizes, int n_in,
                              void* d_out, int out_size, void* d_ws, size_t ws_size,
                              hipStream_t stream) {
  const float* x    = (const float*)d_in[0];
  const float* y0   = (const float*)d_in[1];
  const float* wihE = (const float*)d_in[2];
  const float* whhE = (const float*)d_in[3];
  const float* bihE = (const float*)d_in[4];
  const float* bhhE = (const float*)d_in[5];
  const float* wihD = (const float*)d_in[6];
  const float* whhD = (const float*)d_in[7];
  const float* bihD = (const float*)d_in[8];
  const float* bhhD = (const float*)d_in[9];
  const float* wfc  = (const float*)d_in[10];
  const float* bfc  = (const float*)d_in[11];
  char* ws   = (char*)d_ws;
  float* out = (float*)d_out;

  // idempotent, called every launch (no static guards allowed)
  (void)hipFuncSetAttribute((const void*)lstm_persist,
                            hipFuncAttributeMaxDynamicSharedMemorySize, LDS_BYTES);

  prologue<<<256, 256, 0, stream>>>(x, y0, wihE, whhE, bihE, bhhE,
                                    wihD, whhD, bihD, bhhD, wfc, ws);
  lstm_persist<<<NWG, 256, LDS_BYTES, stream>>>(ws, out, bfc);
}

// Round 6
// 3682.841 us; speedup vs baseline: 1.7483x; 1.7483x over previous
//
#include <hip/hip_runtime.h>
#include <hip/hip_fp16.h>

typedef _Float16 f16;
typedef _Float16 f16x8 __attribute__((ext_vector_type(8)));
typedef float f32x16 __attribute__((ext_vector_type(16)));

#define T_N 512
#define DSTEPS 48
#define TOTSTEPS 560
#define NWG 128

// ---- ws layout (bytes) ----
#define OFF_WHHE 0ull
#define SZ_WHH   (4096ull*1024*2)          // 8 MB
#define OFF_WHHD (OFF_WHHE + SZ_WHH)
#define OFF_WIHE (OFF_WHHD + SZ_WHH)
#define SZ_WIH   (4096ull*64*2)            // 512 KB
#define OFF_WIHD (OFF_WIHE + SZ_WIH)
#define OFF_WFC  (OFF_WIHD + SZ_WIH)
#define SZ_WFC   (64ull*1024*2)            // 128 KB
#define OFF_XP   (OFF_WFC + SZ_WFC)
#define SZ_XP    (512ull*4096*2)           // 4 MB
#define OFF_Y0   (OFF_XP + SZ_XP)
#define SZ_Y0    (4096ull*2)
#define OFF_BE   (OFF_Y0 + SZ_Y0)
#define OFF_BD   (OFF_BE + 4096ull*4)
#define OFF_FLG  (OFF_BD + 4096ull*4)
#define SZ_FLG   (561ull*128*4)            // flags[t][g][w]
#define OFF_H    ((OFF_FLG + SZ_FLG + 255ull) & ~255ull)
// h of step t: 65536 f16 at OFF_H + t*131072; group g at +g*32768 f16,
// group layout [w_src(64)][b(32)][u(16)]

// ============================ prologue: pack to fp16 fragment-linear ============================
__global__ void prologue(const float* __restrict__ x, const float* __restrict__ y0,
    const float* __restrict__ wihE, const float* __restrict__ whhE,
    const float* __restrict__ bihE, const float* __restrict__ bhhE,
    const float* __restrict__ wihD, const float* __restrict__ whhD,
    const float* __restrict__ bihD, const float* __restrict__ bhhD,
    const float* __restrict__ wfc, char* __restrict__ ws)
{
  const long long gid = (long long)blockIdx.x * 256 + threadIdx.x;
  const long long gsz = (long long)gridDim.x * 256;
  f16* whhEp = (f16*)(ws + OFF_WHHE);
  f16* whhDp = (f16*)(ws + OFF_WHHD);
  f16* wihEp = (f16*)(ws + OFF_WIHE);
  f16* wihDp = (f16*)(ws + OFF_WIHD);
  f16* wfcp  = (f16*)(ws + OFF_WFC);
  f16* xp    = (f16*)(ws + OFF_XP);
  f16* y0p   = (f16*)(ws + OFF_Y0);
  float* be  = (float*)(ws + OFF_BE);
  float* bd  = (float*)(ws + OFF_BD);

  // Whh packs: idx = w*65536 + ks*32768 + i*16384 + kk*512 + lane*8 + j
  for (long long idx = gid; idx < 4194304ll; idx += gsz) {
    int j = (int)idx & 7, l = (int)(idx >> 3) & 63, kk = (int)(idx >> 9) & 31;
    int i = (int)(idx >> 14) & 1, ks = (int)(idx >> 15) & 1, w = (int)(idx >> 16);
    int nl = i * 32 + (l & 31);
    int grow = (nl >> 4) * 1024 + w * 16 + (nl & 15);
    int k = ks * 512 + kk * 16 + ((l >> 5) << 3) + j;
    whhEp[idx] = (f16)whhE[(long long)grow * 1024 + k];
    whhDp[idx] = (f16)whhD[(long long)grow * 1024 + k];
  }
  // Wih packs: idx = w*4096 + ks*2048 + i*1024 + kx*512 + lane*8 + j
  for (long long idx = gid; idx < 262144ll; idx += gsz) {
    int j = (int)idx & 7, l = (int)(idx >> 3) & 63, kx = (int)(idx >> 9) & 1;
    int i = (int)(idx >> 10) & 1, ks = (int)(idx >> 11) & 1, w = (int)(idx >> 12);
    int nl = i * 32 + (l & 31);
    int grow = (nl >> 4) * 1024 + w * 16 + (nl & 15);
    int k = (ks * 2 + kx) * 16 + ((l >> 5) << 3) + j;
    wihEp[idx] = (f16)wihE[grow * 64 + k];
    wihDp[idx] = (f16)wihD[grow * 64 + k];
  }
  // Wfc pack: idx = ks*32768 + i*16384 + kk*512 + lane*8 + j
  for (long long idx = gid; idx < 65536ll; idx += gsz) {
    int j = (int)idx & 7, l = (int)(idx >> 3) & 63, kk = (int)(idx >> 9) & 31;
    int i = (int)(idx >> 14) & 1, ks = (int)(idx >> 15) & 1;
    int o = i * 32 + (l & 31);
    int k = ks * 512 + kk * 16 + ((l >> 5) << 3) + j;
    wfcp[idx] = (f16)wfc[o * 1024 + k];
  }
  // x pack: [t][kkx(4)][b(64)][16]
  for (long long idx = gid; idx < 2097152ll; idx += gsz) {
    int kw = (int)idx & 15, b = (int)(idx >> 4) & 63, kkx = (int)(idx >> 10) & 3, t = (int)(idx >> 12);
    xp[idx] = (f16)x[(long long)b * 32768 + t * 64 + kkx * 16 + kw];
  }
  // y0 pack: [kkx][b][16]
  for (long long idx = gid; idx < 4096ll; idx += gsz) {
    int kw = (int)idx & 15, b = (int)(idx >> 4) & 63, kkx = (int)(idx >> 10) & 3;
    y0p[idx] = (f16)y0[b * 64 + kkx * 16 + kw];
  }
  // combined biases
  for (long long idx = gid; idx < 4096ll; idx += gsz) {
    be[idx] = bihE[idx] + bhhE[idx];
    bd[idx] = bihD[idx] + bhhD[idx];
  }
  // flags need no init: poison 0xAAAAAAAA != 1, producers store 1
}

// ============================ persistent LSTM kernel ============================
__device__ __forceinline__ float sigf(float x) { return 1.0f / (1.0f + __expf(-x)); }
__device__ __forceinline__ float tanhfast(float x) {
  x = fminf(fmaxf(x, -15.f), 15.f);
  float e = __expf(2.0f * x);
  return (e - 1.0f) / (e + 1.0f);
}

#define MFMA(a,b,c) __builtin_amdgcn_mfma_f32_32x32x16_f16((a),(b),(c),0,0,0)

__launch_bounds__(256, 1)
__global__ void lstm_persist(char* __restrict__ ws, float* __restrict__ out,
                             const float* __restrict__ bfc)
{
  const int w    = blockIdx.x & 63;   // n-slice: hidden units [w*16, w*16+16)
  const int g    = blockIdx.x >> 6;   // batch group: batches [g*32, g*32+32)
  const int tid  = threadIdx.x;
  const int lane = tid & 63;
  const int q    = tid >> 6;          // wave = K-quarter (k in [256q, 256q+256))

  const f16* whhEp = (const f16*)(ws + OFF_WHHE) + (size_t)w * 65536;
  const f16* whhDp = (const f16*)(ws + OFF_WHHD) + (size_t)w * 65536;
  const f16* wihEp = (const f16*)(ws + OFF_WIHE) + (size_t)w * 4096;
  const f16* wihDp = (const f16*)(ws + OFF_WIHD) + (size_t)w * 4096;
  const f16* wfcp  = (const f16*)(ws + OFF_WFC);
  const f16* xp    = (const f16*)(ws + OFF_XP);
  const f16* y0p   = (const f16*)(ws + OFF_Y0);
  const float* be  = (const float*)(ws + OFF_BE);
  const float* bd  = (const float*)(ws + OFF_BD);
  unsigned* flags  = (unsigned*)(ws + OFF_FLG);
  f16* hb          = (f16*)(ws + OFF_H);

  __shared__ float lds_g[4][64][34];   // [K-quarter][gate-row n][batch m]
  __shared__ float bias_s[2][64];

  if (tid < 64) {
    int g4 = tid >> 4, u = tid & 15;
    bias_s[0][tid] = be[g4 * 1024 + w * 16 + u];
    bias_s[1][tid] = bd[g4 * 1024 + w * 16 + u];
  }

  // A-frag offsets
  const int aoff_x = (g * 32 + (lane & 31)) * 16 + (lane >> 5) * 8;  // x pack has b(64)
  const int aoff_h = (lane & 31) * 16 + (lane >> 5) * 8;             // h group block has b(32)
  const int boff   = lane * 8;
  const int bq     = (q >> 1) * 32768 + (q & 1) * 8192;   // K-quarter base in Whh/Wfc pack
  const int wq     = (q >> 1) * 2048 + (q & 1) * 512;     // K-quarter base in Wih pack
  // cell phase: thread -> (batch bsel in group, units u0,u0+1)
  const int bsel = tid >> 3;
  const int u0   = (tid & 7) * 2;

  // Whh B-fragments resident in registers: [n-tile][kk]
  f16x8 bf0[16], bf1[16];
#pragma unroll
  for (int kk = 0; kk < 16; ++kk) {
    bf0[kk] = *(const f16x8*)(whhEp + bq + kk * 512 + boff);
    bf1[kk] = *(const f16x8*)(whhEp + bq + 16384 + kk * 512 + boff);
  }

  float cA = 0.f, cB = 0.f;
  __syncthreads();   // bias_s ready

#pragma unroll 1
  for (int t = 0; t < TOTSTEPS; ++t) {
    const bool enc = (t < T_N);
    if (t == T_N) {   // register-only decoder weight swap
#pragma unroll
      for (int kk = 0; kk < 16; ++kk) {
        bf0[kk] = *(const f16x8*)(whhDp + bq + kk * 512 + boff);
        bf1[kk] = *(const f16x8*)(whhDp + bq + 16384 + kk * 512 + boff);
      }
    }

    // x-projection (independent of h) — issued before the wait
    const f16* xblk = enc ? (xp + (size_t)t * 4096) : y0p;
    const f16* wihp = enc ? wihEp : wihDp;
    f16x8 xa  = *(const f16x8*)(xblk + q * 1024 + aoff_x);
    f16x8 wf0 = *(const f16x8*)(wihp + wq + boff);
    f16x8 wf1 = *(const f16x8*)(wihp + wq + 1024 + boff);

    f32x16 a00, a01;
#pragma unroll
    for (int i = 0; i < 16; ++i) { a00[i] = 0.f; a01[i] = 0.f; }
    a00 = MFMA(xa, wf0, a00);
    a01 = MFMA(xa, wf1, a01);

    if (t > 0) {
      // R3-style barrier-paced poll: all 4 waves check all 64 producer flags of group g
      const unsigned* fl = flags + (size_t)t * 128 + g * 64 + lane;
      int ok;
      do {
        unsigned v = __hip_atomic_load(fl, __ATOMIC_RELAXED, __HIP_MEMORY_SCOPE_AGENT);
        ok = (v == 1u);
      } while (__syncthreads_and(ok) == 0);

      // burst-load this wave's K-quarter of group-g h(t-1): 16 x 1KB in flight
      const f16* hblk = hb + (size_t)(t - 1) * 65536 + (size_t)g * 32768;
      f16x8 af[16];
#pragma unroll
      for (int kk = 0; kk < 16; ++kk)
        af[kk] = *(const f16x8*)(hblk + (size_t)(q * 16 + kk) * 512 + aoff_h);
#pragma unroll
      for (int kk = 0; kk < 16; ++kk) {
        a00 = MFMA(af[kk], bf0[kk], a00);
        a01 = MFMA(af[kk], bf1[kk], a01);
      }
    }

    // K-quarter partials -> LDS (pattern identical to R3's measured-clean one)
    {
      const int n0 = lane & 31;
      const int mb = (lane >> 5) << 2;
#pragma unroll
      for (int r = 0; r < 16; ++r) {
        const int m0 = mb + (r & 3) + ((r >> 2) << 3);
        lds_g[q][n0][m0]      = a00[r];
        lds_g[q][32 + n0][m0] = a01[r];
      }
    }
    __syncthreads();

    // cell update: thread -> (batch bsel, units u0,u0+1); c in fp32 regs
    const float* bs = enc ? bias_s[0] : bias_s[1];
    union { unsigned u32; f16 h2[2]; } hu;
    float cc[2] = {cA, cB};
#pragma unroll
    for (int j = 0; j < 2; ++j) {
      const int u = u0 + j;
      float ig = lds_g[0][u][bsel]      + lds_g[1][u][bsel]      + lds_g[2][u][bsel]      + lds_g[3][u][bsel]      + bs[u];
      float fg = lds_g[0][16 + u][bsel] + lds_g[1][16 + u][bsel] + lds_g[2][16 + u][bsel] + lds_g[3][16 + u][bsel] + bs[16 + u];
      float gg = lds_g[0][32 + u][bsel] + lds_g[1][32 + u][bsel] + lds_g[2][32 + u][bsel] + lds_g[3][32 + u][bsel] + bs[32 + u];
      float og = lds_g[0][48 + u][bsel] + lds_g[1][48 + u][bsel] + lds_g[2][48 + u][bsel] + lds_g[3][48 + u][bsel] + bs[48 + u];
      float cn = sigf(fg) * cc[j] + sigf(ig) * tanhfast(gg);
      cc[j] = cn;
      hu.h2[j] = (f16)(sigf(og) * tanhfast(cn));
    }
    cA = cc[0]; cB = cc[1];

    // contiguous write-through h slice (1KB per WG), then full-WG drain + one flag
    {
      f16* dst = hb + (size_t)t * 65536 + (size_t)g * 32768 + (size_t)w * 512 + bsel * 16 + u0;
      unsigned long long addr = (unsigned long long)(size_t)dst;
      asm volatile("global_store_dword %0, %1, off sc0 sc1" : : "v"(addr), "v"(hu.u32) : "memory");
    }
    asm volatile("s_waitcnt vmcnt(0)" ::: "memory");
    __syncthreads();
    if (tid == 0) {
      __hip_atomic_store(flags + (size_t)(t + 1) * 128 + g * 64 + w, 1u,
                         __ATOMIC_RELEASE, __HIP_MEMORY_SCOPE_AGENT);
    }
  }

  // ---- FC epilogue: WG (g, w<48) -> out[g*32..+32, w*64..+64) from h of step 512+w ----
  if (w < DSTEPS) {
    const int s = T_N + 1 + w;   // flag index of h produced at step 512+w
#pragma unroll
    for (int kk = 0; kk < 16; ++kk) {
      bf0[kk] = *(const f16x8*)(wfcp + bq + kk * 512 + boff);
      bf1[kk] = *(const f16x8*)(wfcp + bq + 16384 + kk * 512 + boff);
    }
    {
      const unsigned* fl = flags + (size_t)s * 128 + g * 64 + lane;
      int ok;
      do {
        unsigned v = __hip_atomic_load(fl, __ATOMIC_RELAXED, __HIP_MEMORY_SCOPE_AGENT);
        ok = (v == 1u);
      } while (__syncthreads_and(ok) == 0);
    }
    const f16* hblk = hb + (size_t)(s - 1) * 65536 + (size_t)g * 32768;
    f16x8 af[16];
#pragma unroll
    for (int kk = 0; kk < 16; ++kk)
      af[kk] = *(const f16x8*)(hblk + (size_t)(q * 16 + kk) * 512 + aoff_h);

    f32x16 a00, a01;
#pragma unroll
    for (int i = 0; i < 16; ++i) { a00[i] = 0.f; a01[i] = 0.f; }
#pragma unroll
    for (int kk = 0; kk < 16; ++kk) {
      a00 = MFMA(af[kk], bf0[kk], a00);
      a01 = MFMA(af[kk], bf1[kk], a01);
    }
    {
      const int n0 = lane & 31;
      const int mb = (lane >> 5) << 2;
#pragma unroll
      for (int r = 0; r < 16; ++r) {
        const int m0 = mb + (r & 3) + ((r >> 2) << 3);
        lds_g[q][n0][m0]      = a00[r];
        lds_g[q][32 + n0][m0] = a01[r];
      }
    }
    __syncthreads();
    // thread -> batch bsel, features f0..f0+7 (8 thread-cols x 8 features = all 64)
    const int f0 = (tid & 7) * 8;
    float of[8];
#pragma unroll
    for (int j = 0; j < 8; ++j) {
      const int f = f0 + j;
      of[j] = lds_g[0][f][bsel] + lds_g[1][f][bsel] + lds_g[2][f][bsel] + lds_g[3][f][bsel] + bfc[f];
    }
    float* op = out + (size_t)(g * 32 + bsel) * 3072 + w * 64 + f0;
    *(float4*)(op)     = make_float4(of[0], of[1], of[2], of[3]);
    *(float4*)(op + 4) = make_float4(of[4], of[5], of[6], of[7]);
  }
}

// ============================ launch ============================
extern "C" void kernel_launch(void* const* d_in, const int* in_sizes, int n_in,
                              void* d_out, int out_size, void* d_ws, size_t ws_size,
                              hipStream_t stream) {
  const float* x    = (const float*)d_in[0];
  const float* y0   = (const float*)d_in[1];
  const float* wihE = (const float*)d_in[2];
  const float* whhE = (const float*)d_in[3];
  const float* bihE = (const float*)d_in[4];
  const float* bhhE = (const float*)d_in[5];
  const float* wihD = (const float*)d_in[6];
  const float* whhD = (const float*)d_in[7];
  const float* bihD = (const float*)d_in[8];
  const float* bhhD = (const float*)d_in[9];
  const float* wfc  = (const float*)d_in[10];
  const float* bfc  = (const float*)d_in[11];
  char* ws   = (char*)d_ws;
  float* out = (float*)d_out;

  prologue<<<256, 256, 0, stream>>>(x, y0, wihE, whhE, bihE, bhhE,
                                    wihD, whhD, bihD, bhhD, wfc, ws);
  lstm_persist<<<NWG, 256, 0, stream>>>(ws, out, bfc);
}

// Round 7
// 3327.425 us; speedup vs baseline: 1.9350x; 1.1068x over previous
//
#include <hip/hip_runtime.h>
#include <hip/hip_fp16.h>

typedef _Float16 f16;
typedef _Float16 f16x8 __attribute__((ext_vector_type(8)));
typedef float f32x16 __attribute__((ext_vector_type(16)));

#define T_N 512
#define DSTEPS 48
#define TOTSTEPS 560
#define NWG 64

// ---- ws layout (bytes) ----
#define OFF_WHHE 0ull
#define SZ_WHH   (4096ull*1024*2)          // 8 MB
#define OFF_WHHD (OFF_WHHE + SZ_WHH)
#define OFF_WIHE (OFF_WHHD + SZ_WHH)
#define SZ_WIH   (4096ull*64*2)            // 512 KB
#define OFF_WIHD (OFF_WIHE + SZ_WIH)
#define OFF_WFC  (OFF_WIHD + SZ_WIH)
#define SZ_WFC   (64ull*1024*2)            // 128 KB
#define OFF_XP   (OFF_WFC + SZ_WFC)
#define SZ_XP    (512ull*4096*2)           // 4 MB
#define OFF_Y0   (OFF_XP + SZ_XP)
#define SZ_Y0    (4096ull*2)
#define OFF_BE   (OFF_Y0 + SZ_Y0)
#define OFF_BD   (OFF_BE + 4096ull*4)
#define OFF_FLG  (OFF_BD + 4096ull*4)
#define SZ_FLG   (561ull*256*4)            // flags[t][q(4)][w(64)], per producer-wave
#define OFF_H    ((OFF_FLG + SZ_FLG + 255ull) & ~255ull)
// h produced at step t: 65536 f16 at OFF_H + t*131072, layout [w_src(64)][b(64)][u(16)]

// ============================ prologue: pack to fp16 fragment-linear ============================
// Fragment indexing for wave (wm, ks):
//   B-frag (Whh): idx = w*65536 + ks*32768 + i*16384 + kk*512 + lane*8 + j
//     maps to Whh[gate*1024 + w*16 + unit][ks*512 + kk*16 + (lane>>5)*8 + j],
//     with n_local = i*32 + (lane&31) = gate*16 + unit
//   Wih frag:     idx = w*4096 + ks*2048 + i*1024 + kx*512 + lane*8 + j
//   Wfc frag:     idx = ks*32768 + i*16384 + kk*512 + lane*8 + j
__global__ void prologue(const float* __restrict__ x, const float* __restrict__ y0,
    const float* __restrict__ wihE, const float* __restrict__ whhE,
    const float* __restrict__ bihE, const float* __restrict__ bhhE,
    const float* __restrict__ wihD, const float* __restrict__ whhD,
    const float* __restrict__ bihD, const float* __restrict__ bhhD,
    const float* __restrict__ wfc, char* __restrict__ ws)
{
  const long long gid = (long long)blockIdx.x * 256 + threadIdx.x;
  const long long gsz = (long long)gridDim.x * 256;
  f16* whhEp = (f16*)(ws + OFF_WHHE);
  f16* whhDp = (f16*)(ws + OFF_WHHD);
  f16* wihEp = (f16*)(ws + OFF_WIHE);
  f16* wihDp = (f16*)(ws + OFF_WIHD);
  f16* wfcp  = (f16*)(ws + OFF_WFC);
  f16* xp    = (f16*)(ws + OFF_XP);
  f16* y0p   = (f16*)(ws + OFF_Y0);
  float* be  = (float*)(ws + OFF_BE);
  float* bd  = (float*)(ws + OFF_BD);

  // Whh packs (4,194,304 f16 each)
  for (long long idx = gid; idx < 4194304ll; idx += gsz) {
    int j = (int)idx & 7, l = (int)(idx >> 3) & 63, kk = (int)(idx >> 9) & 31;
    int i = (int)(idx >> 14) & 1, ks = (int)(idx >> 15) & 1, w = (int)(idx >> 16);
    int nl = i * 32 + (l & 31);
    int grow = (nl >> 4) * 1024 + w * 16 + (nl & 15);
    int k = ks * 512 + kk * 16 + ((l >> 5) << 3) + j;
    whhEp[idx] = (f16)whhE[(long long)grow * 1024 + k];
    whhDp[idx] = (f16)whhD[(long long)grow * 1024 + k];
  }
  // Wih packs (262,144 each)
  for (long long idx = gid; idx < 262144ll; idx += gsz) {
    int j = (int)idx & 7, l = (int)(idx >> 3) & 63, kx = (int)(idx >> 9) & 1;
    int i = (int)(idx >> 10) & 1, ks = (int)(idx >> 11) & 1, w = (int)(idx >> 12);
    int nl = i * 32 + (l & 31);
    int grow = (nl >> 4) * 1024 + w * 16 + (nl & 15);
    int k = (ks * 2 + kx) * 16 + ((l >> 5) << 3) + j;
    wihEp[idx] = (f16)wihE[grow * 64 + k];
    wihDp[idx] = (f16)wihD[grow * 64 + k];
  }
  // Wfc pack (65,536)
  for (long long idx = gid; idx < 65536ll; idx += gsz) {
    int j = (int)idx & 7, l = (int)(idx >> 3) & 63, kk = (int)(idx >> 9) & 31;
    int i = (int)(idx >> 14) & 1, ks = (int)(idx >> 15) & 1;
    int o = i * 32 + (l & 31);
    int k = ks * 512 + kk * 16 + ((l >> 5) << 3) + j;
    wfcp[idx] = (f16)wfc[o * 1024 + k];
  }
  // x pack: [t][kkx(4)][b(64)][16]
  for (long long idx = gid; idx < 2097152ll; idx += gsz) {
    int kw = (int)idx & 15, b = (int)(idx >> 4) & 63, kkx = (int)(idx >> 10) & 3, t = (int)(idx >> 12);
    xp[idx] = (f16)x[(long long)b * 32768 + t * 64 + kkx * 16 + kw];
  }
  // y0 pack: [kkx][b][16]
  for (long long idx = gid; idx < 4096ll; idx += gsz) {
    int kw = (int)idx & 15, b = (int)(idx >> 4) & 63, kkx = (int)(idx >> 10) & 3;
    y0p[idx] = (f16)y0[b * 64 + kkx * 16 + kw];
  }
  // combined biases
  for (long long idx = gid; idx < 4096ll; idx += gsz) {
    be[idx] = bihE[idx] + bhhE[idx];
    bd[idx] = bihD[idx] + bhhD[idx];
  }
  // flags need no init: poison 0xAAAAAAAA != 1, producers store 1
}

// ============================ persistent LSTM kernel ============================
__device__ __forceinline__ float sigf(float x) { return 1.0f / (1.0f + __expf(-x)); }
__device__ __forceinline__ float tanhfast(float x) {
  x = fminf(fmaxf(x, -15.f), 15.f);
  float e = __expf(2.0f * x);
  return (e - 1.0f) / (e + 1.0f);
}

#define MFMA(a,b,c) __builtin_amdgcn_mfma_f32_32x32x16_f16((a),(b),(c),0,0,0)

__launch_bounds__(256, 1)
__global__ void lstm_persist(char* __restrict__ ws, float* __restrict__ out,
                             const float* __restrict__ bfc)
{
  const int w    = blockIdx.x;      // owns hidden units [w*16, w*16+16)
  const int tid  = threadIdx.x;
  const int lane = tid & 63;
  const int wave = tid >> 6;
  const int wm   = wave & 1;        // M-half (batch 0..31 / 32..63)
  const int ks   = wave >> 1;       // K-half (h units 0..511 / 512..1023)

  const f16* whhEp = (const f16*)(ws + OFF_WHHE) + (size_t)w * 65536;
  const f16* whhDp = (const f16*)(ws + OFF_WHHD) + (size_t)w * 65536;
  const f16* wihEp = (const f16*)(ws + OFF_WIHE) + (size_t)w * 4096;
  const f16* wihDp = (const f16*)(ws + OFF_WIHD) + (size_t)w * 4096;
  const f16* wfcp  = (const f16*)(ws + OFF_WFC);
  const f16* xp    = (const f16*)(ws + OFF_XP);
  const f16* y0p   = (const f16*)(ws + OFF_Y0);
  const float* be  = (const float*)(ws + OFF_BE);
  const float* bd  = (const float*)(ws + OFF_BD);
  unsigned* flags  = (unsigned*)(ws + OFF_FLG);
  f16* hb          = (f16*)(ws + OFF_H);

  __shared__ float lds_g[2][64][66];   // [ks][gate-row n][batch m], padded (R3-measured clean)
  __shared__ float bias_s[2][64];

  if (tid < 64) {
    int g4 = tid >> 4, u = tid & 15;
    bias_s[0][tid] = be[g4 * 1024 + w * 16 + u];
    bias_s[1][tid] = bd[g4 * 1024 + w * 16 + u];
  }

  // A-frag offset inside a [64b][16k] K-block: row=wm*32+(lane&31), khalf=(lane>>5)
  const int aoff = (wm * 32 + (lane & 31)) * 16 + (lane >> 5) * 8;
  const int boff = lane * 8;          // lane-linear packed B
  const int bsel = tid >> 2;          // batch this thread updates (cell phase)
  const int u0   = (tid & 3) * 4;     // first of 4 owned unit-locals

  // Whh B-fragments (compiler streams these from L2 each step; addresses loop-invariant)
  f16x8 bf0[32], bf1[32];
#pragma unroll
  for (int kk = 0; kk < 32; ++kk) {
    bf0[kk] = *(const f16x8*)(whhEp + (size_t)ks * 32768 + kk * 512 + boff);
    bf1[kk] = *(const f16x8*)(whhEp + (size_t)ks * 32768 + 16384 + kk * 512 + boff);
  }

  float c0 = 0.f, c1 = 0.f, c2 = 0.f, c3 = 0.f;
  __syncthreads();

#pragma unroll 1
  for (int t = 0; t < TOTSTEPS; ++t) {
    const bool enc = (t < T_N);

    if (t == T_N) {   // decoder weight swap (register/stream only)
#pragma unroll
      for (int kk = 0; kk < 32; ++kk) {
        bf0[kk] = *(const f16x8*)(whhDp + (size_t)ks * 32768 + kk * 512 + boff);
        bf1[kk] = *(const f16x8*)(whhDp + (size_t)ks * 32768 + 16384 + kk * 512 + boff);
      }
    }

    // x-projection operands (independent of h -> issue before the wait)
    const f16* xblk = enc ? (xp + (size_t)t * 4096) : y0p;
    const f16* wihp = enc ? wihEp : wihDp;
    f16x8 xa0 = *(const f16x8*)(xblk + (ks * 2 + 0) * 1024 + aoff);
    f16x8 xa1 = *(const f16x8*)(xblk + (ks * 2 + 1) * 1024 + aoff);
    f16x8 wf0 = *(const f16x8*)(wihp + ((ks * 2 + 0) * 2 + 0) * 512 + boff);
    f16x8 wf1 = *(const f16x8*)(wihp + ((ks * 2 + 0) * 2 + 1) * 512 + boff);
    f16x8 wf2 = *(const f16x8*)(wihp + ((ks * 2 + 1) * 2 + 0) * 512 + boff);
    f16x8 wf3 = *(const f16x8*)(wihp + ((ks * 2 + 1) * 2 + 1) * 512 + boff);

    // wait for all 256 producer-wave flags of h(t-1) (barrier-paced, R3-style)
    if (t > 0) {
      const unsigned* fp0 = flags + (size_t)t * 256 + lane;
      int ok;
      do {
        unsigned v0 = __hip_atomic_load(fp0,       __ATOMIC_RELAXED, __HIP_MEMORY_SCOPE_AGENT);
        unsigned v1 = __hip_atomic_load(fp0 + 64,  __ATOMIC_RELAXED, __HIP_MEMORY_SCOPE_AGENT);
        unsigned v2 = __hip_atomic_load(fp0 + 128, __ATOMIC_RELAXED, __HIP_MEMORY_SCOPE_AGENT);
        unsigned v3 = __hip_atomic_load(fp0 + 192, __ATOMIC_RELAXED, __HIP_MEMORY_SCOPE_AGENT);
        ok = (v0 == 1u) & (v1 == 1u) & (v2 == 1u) & (v3 == 1u);
      } while (__syncthreads_and(ok) == 0);
    }

    // ---- burst-load this wave's A quarter of h(t-1): 32 x 16B, all in flight ----
    f16x8 af[32];
    if (t > 0) {
      const f16* hblk = hb + (size_t)(t - 1) * 65536;
#pragma unroll
      for (int kk = 0; kk < 32; ++kk)
        af[kk] = *(const f16x8*)(hblk + (size_t)(ks * 32 + kk) * 1024 + aoff);
    }

    f32x16 acc0, acc1;
#pragma unroll
    for (int i = 0; i < 16; ++i) { acc0[i] = 0.f; acc1[i] = 0.f; }
    acc0 = MFMA(xa0, wf0, acc0); acc0 = MFMA(xa1, wf1, acc0);
    acc1 = MFMA(xa0, wf2, acc1); acc1 = MFMA(xa1, wf3, acc1);

    if (t > 0) {
#pragma unroll
      for (int kk = 0; kk < 32; ++kk) {
        acc0 = MFMA(af[kk], bf0[kk], acc0);
        acc1 = MFMA(af[kk], bf1[kk], acc1);
      }
    }

    // K-split partials to LDS
    {
      const int n0 = lane & 31;
      const int mb = wm * 32 + ((lane >> 5) << 2);
#pragma unroll
      for (int r = 0; r < 16; ++r) {
        const int m = mb + (r & 3) + ((r >> 2) << 3);
        lds_g[ks][n0][m]      = acc0[r];
        lds_g[ks][32 + n0][m] = acc1[r];
      }
    }
    __syncthreads();

    // cell update: thread -> (batch bsel, unit-locals u0..u0+3); c in fp32 regs
    const float* bs = enc ? bias_s[0] : bias_s[1];
    union { unsigned long long u64; f16 h4[4]; } hu;
    float cc[4] = {c0, c1, c2, c3};
#pragma unroll
    for (int j = 0; j < 4; ++j) {
      const int u = u0 + j;
      float ig = lds_g[0][u][bsel]      + lds_g[1][u][bsel]      + bs[u];
      float fg = lds_g[0][16 + u][bsel] + lds_g[1][16 + u][bsel] + bs[16 + u];
      float gg = lds_g[0][32 + u][bsel] + lds_g[1][32 + u][bsel] + bs[32 + u];
      float og = lds_g[0][48 + u][bsel] + lds_g[1][48 + u][bsel] + bs[48 + u];
      float cn = sigf(fg) * cc[j] + sigf(ig) * tanhfast(gg);
      cc[j] = cn;
      hu.h4[j] = (f16)(sigf(og) * tanhfast(cn));
    }
    c0 = cc[0]; c1 = cc[1]; c2 = cc[2]; c3 = cc[3];

    // write-through h slice: thread -> bytes [tid*8, tid*8+8); wave covers contiguous 512B
    {
      f16* dst = hb + (size_t)t * 65536 + (size_t)w * 1024 + bsel * 16 + u0;
      unsigned long long addr = (unsigned long long)(size_t)dst;
      asm volatile("global_store_dwordx2 %0, %1, off sc0 sc1" : : "v"(addr), "v"(hu.u64) : "memory");
    }
    // wave-local drain, then this wave's own flag — no workgroup barrier on the signal path
    asm volatile("s_waitcnt vmcnt(0)" ::: "memory");
    if (lane == 0) {
      unsigned* fa = flags + (size_t)(t + 1) * 256 + wave * 64 + w;
      unsigned long long addr = (unsigned long long)(size_t)fa;
      unsigned one = 1u;
      asm volatile("global_store_dword %0, %1, off sc0 sc1" : : "v"(addr), "v"(one) : "memory");
    }
    // (LDS WAR safety for t+1: a wave passes the t+1 poll only after ALL sibling
    //  waves flagged t+1, which happens after their step-t LDS cell reads.)
  }

  // ---- FC epilogue: WG w<48 computes out[:, w*64..+64) from h of step 512+w ----
  if (w < DSTEPS) {
    const int s = T_N + 1 + w;   // flag index of h produced at step 512+w
#pragma unroll
    for (int kk = 0; kk < 32; ++kk) {
      bf0[kk] = *(const f16x8*)(wfcp + (size_t)ks * 32768 + kk * 512 + boff);
      bf1[kk] = *(const f16x8*)(wfcp + (size_t)ks * 32768 + 16384 + kk * 512 + boff);
    }
    {
      const unsigned* fp0 = flags + (size_t)s * 256 + lane;
      int ok;
      do {
        unsigned v0 = __hip_atomic_load(fp0,       __ATOMIC_RELAXED, __HIP_MEMORY_SCOPE_AGENT);
        unsigned v1 = __hip_atomic_load(fp0 + 64,  __ATOMIC_RELAXED, __HIP_MEMORY_SCOPE_AGENT);
        unsigned v2 = __hip_atomic_load(fp0 + 128, __ATOMIC_RELAXED, __HIP_MEMORY_SCOPE_AGENT);
        unsigned v3 = __hip_atomic_load(fp0 + 192, __ATOMIC_RELAXED, __HIP_MEMORY_SCOPE_AGENT);
        ok = (v0 == 1u) & (v1 == 1u) & (v2 == 1u) & (v3 == 1u);
      } while (__syncthreads_and(ok) == 0);
    }
    const f16* hblk = hb + (size_t)(s - 1) * 65536;
    f16x8 af[32];
#pragma unroll
    for (int kk = 0; kk < 32; ++kk)
      af[kk] = *(const f16x8*)(hblk + (size_t)(ks * 32 + kk) * 1024 + aoff);

    f32x16 acc0, acc1;
#pragma unroll
    for (int i = 0; i < 16; ++i) { acc0[i] = 0.f; acc1[i] = 0.f; }
#pragma unroll
    for (int kk = 0; kk < 32; ++kk) {
      acc0 = MFMA(af[kk], bf0[kk], acc0);
      acc1 = MFMA(af[kk], bf1[kk], acc1);
    }
    {
      const int n0 = lane & 31;
      const int mb = wm * 32 + ((lane >> 5) << 2);
#pragma unroll
      for (int r = 0; r < 16; ++r) {
        const int m = mb + (r & 3) + ((r >> 2) << 3);
        lds_g[ks][n0][m]      = acc0[r];
        lds_g[ks][32 + n0][m] = acc1[r];
      }
    }
    __syncthreads();
    // thread -> batch bsel, features f0..f0+15 (ALL 64 features covered)
    const int f0 = (tid & 3) * 16;
    float* op = out + (size_t)bsel * 3072 + w * 64 + f0;
#pragma unroll
    for (int c4 = 0; c4 < 4; ++c4) {
      float v4[4];
#pragma unroll
      for (int j = 0; j < 4; ++j) {
        const int f = f0 + c4 * 4 + j;
        v4[j] = lds_g[0][f][bsel] + lds_g[1][f][bsel] + bfc[f];
      }
      *(float4*)(op + c4 * 4) = make_float4(v4[0], v4[1], v4[2], v4[3]);
    }
  }
}

// ============================ launch ============================
extern "C" void kernel_launch(void* const* d_in, const int* in_sizes, int n_in,
                              void* d_out, int out_size, void* d_ws, size_t ws_size,
                              hipStream_t stream) {
  const float* x    = (const float*)d_in[0];
  const float* y0   = (const float*)d_in[1];
  const float* wihE = (const float*)d_in[2];
  const float* whhE = (const float*)d_in[3];
  const float* bihE = (const float*)d_in[4];
  const float* bhhE = (const float*)d_in[5];
  const float* wihD = (const float*)d_in[6];
  const float* whhD = (const float*)d_in[7];
  const float* bihD = (const float*)d_in[8];
  const float* bhhD = (const float*)d_in[9];
  const float* wfc  = (const float*)d_in[10];
  const float* bfc  = (const float*)d_in[11];
  char* ws   = (char*)d_ws;
  float* out = (float*)d_out;

  prologue<<<256, 256, 0, stream>>>(x, y0, wihE, whhE, bihE, bhhE,
                                    wihD, whhD, bihD, bhhD, wfc, ws);
  lstm_persist<<<NWG, 256, 0, stream>>>(ws, out, bfc);
}